// Round 1
// baseline (33.511 us; speedup 1.0000x reference)
//
#include <hip/hip_runtime.h>

#define NBLOCKS 2048
#define TPB 256

// Per-wave (64-lane) + per-block reduction of a double. Result valid in thread 0.
__device__ __forceinline__ double block_reduce_d(double x) {
    #pragma unroll
    for (int off = 32; off > 0; off >>= 1)
        x += __shfl_down(x, off, 64);
    __shared__ double lds[TPB / 64];
    const int lane = threadIdx.x & 63;
    const int wid  = threadIdx.x >> 6;
    if (lane == 0) lds[wid] = x;
    __syncthreads();
    if (wid == 0) {
        x = (lane < (TPB / 64)) ? lds[lane] : 0.0;
        #pragma unroll
        for (int off = (TPB / 128); off > 0; off >>= 1)
            x += __shfl_down(x, off, 64);
    }
    return x;
}

__global__ __launch_bounds__(TPB) void hrl_partial(
    const float* __restrict__ pred,   // [batch, 8]
    const int*   __restrict__ tgt,    // [batch]
    double*      __restrict__ partial,// [NBLOCKS]
    int batch)
{
    const int tid    = blockIdx.x * TPB + threadIdx.x;
    const int stride = gridDim.x * TPB;

    double acc = 0.0;
    for (int i = tid; i < batch; i += stride) {
        const float4* p = reinterpret_cast<const float4*>(pred) + (size_t)i * 2;
        const float4 a = p[0];
        const float4 b = p[1];
        float v[8] = {a.x, a.y, a.z, a.w, b.x, b.y, b.z, b.w};

        // max + first-index argmax (matches jnp.argmax tie-break via strict >)
        float m = v[0];
        int  am = 0;
        #pragma unroll
        for (int j = 1; j < 8; ++j) {
            if (v[j] > m) { m = v[j]; am = j; }
        }

        // sum of exp, and branchless select of v[target] (keep out of scratch)
        const int t = tgt[i];
        float s  = 0.f;
        float vt = 0.f;
        #pragma unroll
        for (int j = 0; j < 8; ++j) {
            s += __expf(v[j] - m);
            vt = (j == t) ? v[j] : vt;
        }

        const float ce  = -(vt - m - __logf(s));
        const float pen = (float)abs(t - am);
        acc += (double)(ce * (1.0f + pen));
    }

    const double bsum = block_reduce_d(acc);
    if (threadIdx.x == 0) partial[blockIdx.x] = bsum;  // overwrite: deterministic per replay
}

__global__ __launch_bounds__(TPB) void hrl_final(
    const double* __restrict__ partial,
    float*        __restrict__ out,
    int nparts, double inv_batch)
{
    double s = 0.0;
    for (int i = threadIdx.x; i < nparts; i += TPB)
        s += partial[i];
    const double tot = block_reduce_d(s);
    if (threadIdx.x == 0) out[0] = (float)(tot * inv_batch);
}

extern "C" void kernel_launch(void* const* d_in, const int* in_sizes, int n_in,
                              void* d_out, int out_size, void* d_ws, size_t ws_size,
                              hipStream_t stream) {
    const float* pred = (const float*)d_in[0];
    const int*   tgt  = (const int*)d_in[1];
    float*  out = (float*)d_out;
    double* ws  = (double*)d_ws;

    const int batch = in_sizes[0] / 8;  // predictions is [batch, 8]

    hrl_partial<<<NBLOCKS, TPB, 0, stream>>>(pred, tgt, ws, batch);
    hrl_final<<<1, TPB, 0, stream>>>(ws, out, NBLOCKS, 1.0 / (double)batch);
}